// Round 1
// baseline (232.891 us; speedup 1.0000x reference)
//
#include <hip/hip_runtime.h>

// ---------------------------------------------------------------------------
// QuantumQKGenerator: out[b, 0..9]=<X_q>, [10..19]=<Y_q>, [20..29]=<Z_q> of
// state S = QFT * U_circuit * normalize(x[b]).  Since x is real and the
// circuit+QFT is a fixed unitary W (depends only on the 40 weights), we:
//   1) build W rows by basis-state simulation + FFT  (cheap)
//   2) transpose to K-contiguous layout for MFMA
//   3) S = Xn @ W  as one fp16 MFMA GEMM  M=8192 N=2048(re/im) K=1024
//   4) reduce expectations from S
// ---------------------------------------------------------------------------

typedef _Float16 half8_t __attribute__((ext_vector_type(8)));
typedef _Float16 half4_t __attribute__((ext_vector_type(4)));
typedef float floatx4 __attribute__((ext_vector_type(4)));

#define GLB_CAST(p) ((const __attribute__((address_space(1))) void*)(p))
#define LDS_CAST(p) ((__attribute__((address_space(3))) void*)(p))

// ---------------------------------------------------------------------------
// Kernel 1: simulate circuit on basis state |j>, then QFT via radix-2 FFT.
// Writes Wh[j][2k]=Re W[j][k], Wh[j][2k+1]=Im W[j][k]  (fp16, [1024][2048]).
// Wire q <-> bit position (9-q)  (wire 0 = MSB).
// ---------------------------------------------------------------------------
__global__ __launch_bounds__(256) void build_w_kernel(const float* __restrict__ w,
                                                      _Float16* __restrict__ Wh)
{
    __shared__ float sr[1024];
    __shared__ float si[1024];
    const int tid = threadIdx.x;
    const int jb  = blockIdx.x;

    for (int i = tid; i < 1024; i += 256) { sr[i] = (i == jb) ? 1.0f : 0.0f; si[i] = 0.0f; }
    __syncthreads();

    // layers: 0=RX(w0), 1=RY(w1), 2=RZ(w2), [CNOT ring], 3=RY(w3)
    for (int layer = 0; layer < 4; ++layer) {
        if (layer == 3) {
            // CNOT ring: control q, target (q+1)%10
            for (int q = 0; q < 10; ++q) {
                int mc = 1 << (9 - q);
                int mt = 1 << (9 - ((q + 1) % 10));
                for (int p = tid; p < 512; p += 256) {
                    int i0 = ((p & ~(mt - 1)) << 1) | (p & (mt - 1)); // target bit = 0
                    if (i0 & mc) {
                        int i1 = i0 | mt;
                        float tr = sr[i0]; sr[i0] = sr[i1]; sr[i1] = tr;
                        float ti = si[i0]; si[i0] = si[i1]; si[i1] = ti;
                    }
                }
                __syncthreads();
            }
        }
        int wi = (layer == 3) ? 3 : layer;
        for (int q = 0; q < 10; ++q) {
            float t = w[q * 4 + wi] * 0.5f;
            float c = cosf(t), s = sinf(t);
            float u00r, u00i, u01r, u01i, u10r, u10i, u11r, u11i;
            if (layer == 0) {        // RX = [[c, -i s],[-i s, c]]
                u00r=c; u00i=0; u01r=0; u01i=-s; u10r=0; u10i=-s; u11r=c; u11i=0;
            } else if (layer == 2) { // RZ = [[e^{-it/2},0],[0,e^{+it/2}]]
                u00r=c; u00i=-s; u01r=0; u01i=0; u10r=0; u10i=0; u11r=c; u11i=s;
            } else {                 // RY = [[c,-s],[s,c]]
                u00r=c; u00i=0; u01r=-s; u01i=0; u10r=s; u10i=0; u11r=c; u11i=0;
            }
            int m = 1 << (9 - q);
            for (int p = tid; p < 512; p += 256) {
                int i0 = ((p & ~(m - 1)) << 1) | (p & (m - 1));
                int i1 = i0 | m;
                float ar = sr[i0], ai = si[i0], br = sr[i1], bi = si[i1];
                sr[i0] = u00r*ar - u00i*ai + u01r*br - u01i*bi;
                si[i0] = u00r*ai + u00i*ar + u01r*bi + u01i*br;
                sr[i1] = u10r*ar - u10i*ai + u11r*br - u11i*bi;
                si[i1] = u10r*ai + u10i*ar + u11r*bi + u11i*br;
            }
            __syncthreads();
        }
    }

    // QFT_MAT[j,k] = exp(+2*pi*i*j*k/1024)/32  -> unnormalized inverse-sign
    // radix-2 DIT FFT (bit-reverse, +i twiddles), then * 1/32.
    for (int i = tid; i < 1024; i += 256) {
        int r = (int)(__brev((unsigned)i) >> 22);
        if (r > i) {
            float tr = sr[i]; sr[i] = sr[r]; sr[r] = tr;
            float ti = si[i]; si[i] = si[r]; si[r] = ti;
        }
    }
    __syncthreads();
    for (int st = 1; st <= 10; ++st) {
        int hf = 1 << (st - 1);
        float astep = 6.28318530717958647f / (float)(1 << st);
        for (int p = tid; p < 512; p += 256) {
            int j2 = p & (hf - 1);
            int i0 = ((p >> (st - 1)) << st) | j2;
            int i1 = i0 + hf;
            float ang = astep * (float)j2;
            float sw, cw;
            __sincosf(ang, &sw, &cw);
            float br2 = sr[i1], bi2 = si[i1];
            float tr = cw*br2 - sw*bi2;
            float ti = cw*bi2 + sw*br2;
            float ur = sr[i0], ui = si[i0];
            sr[i0] = ur + tr; si[i0] = ui + ti;
            sr[i1] = ur - tr; si[i1] = ui - ti;
        }
        __syncthreads();
    }
    for (int k = tid; k < 1024; k += 256) {
        Wh[(size_t)jb * 2048 + 2*k]     = (_Float16)(sr[k] * 0.03125f);
        Wh[(size_t)jb * 2048 + 2*k + 1] = (_Float16)(si[k] * 0.03125f);
    }
}

// ---------------------------------------------------------------------------
// Kernel 1b: Bt[n][j] = Wh[j][n]   ([2048][1024] fp16, K-contiguous rows)
// ---------------------------------------------------------------------------
__global__ __launch_bounds__(256) void transpose_kernel(const _Float16* __restrict__ Wh,
                                                        _Float16* __restrict__ Bt)
{
    __shared__ _Float16 tile[32][33];
    const int bx = blockIdx.x;   // n tile (64)
    const int by = blockIdx.y;   // j tile (32)
    const int tx = threadIdx.x;  // 32
    const int ty = threadIdx.y;  // 8
    #pragma unroll
    for (int i = 0; i < 4; ++i) {
        int r = ty + 8*i;
        tile[r][tx] = Wh[(size_t)(by*32 + r) * 2048 + bx*32 + tx];
    }
    __syncthreads();
    #pragma unroll
    for (int i = 0; i < 4; ++i) {
        int r = ty + 8*i;
        Bt[(size_t)(bx*32 + r) * 1024 + by*32 + tx] = tile[tx][r];
    }
}

// ---------------------------------------------------------------------------
// Kernel 2: row-normalize x (fp32) and store fp16  Xh[8192][1024]
// ---------------------------------------------------------------------------
__global__ __launch_bounds__(256) void normalize_kernel(const float* __restrict__ x,
                                                        _Float16* __restrict__ Xh)
{
    __shared__ float wsum[4];
    const int tid = threadIdx.x;
    const int b = blockIdx.x;
    float4 v = ((const float4*)(x + (size_t)b * 1024))[tid];
    float ss = v.x*v.x + v.y*v.y + v.z*v.z + v.w*v.w;
    #pragma unroll
    for (int off = 32; off; off >>= 1) ss += __shfl_down(ss, off);
    if ((tid & 63) == 0) wsum[tid >> 6] = ss;
    __syncthreads();
    float scale = 1.0f / fmaxf(sqrtf(wsum[0] + wsum[1] + wsum[2] + wsum[3]), 1e-8f);
    half4_t h;
    h[0] = (_Float16)(v.x * scale);
    h[1] = (_Float16)(v.y * scale);
    h[2] = (_Float16)(v.z * scale);
    h[3] = (_Float16)(v.w * scale);
    ((half4_t*)(Xh + (size_t)b * 1024))[tid] = h;
}

// ---------------------------------------------------------------------------
// Kernel 3: GEMM  Sh[8192][2048] = Xh[8192][1024] * Bt^T  (fp16 in, fp32 acc,
// fp16 out).  m97 structure: 128x128 tile, BK=32, global_load_lds width 16,
// 16x16x32 f16 MFMA, 4 waves in 2x2, 4x4 fragments each.
// ---------------------------------------------------------------------------
__global__ __launch_bounds__(256, 2) void gemm_kernel(const _Float16* __restrict__ A,
                                                      const _Float16* __restrict__ Bt,
                                                      _Float16* __restrict__ C)
{
    __shared__ __align__(16) _Float16 As[128][32];
    __shared__ __align__(16) _Float16 Bs[128][32];
    const int tid  = threadIdx.x;
    const int wave = tid >> 6;
    const int lane = tid & 63;
    const int m0 = blockIdx.y * 128;
    const int n0 = blockIdx.x * 128;

    // staging: wave w loads rows [32w, 32w+32) of each tile; lane l -> slot l*16B
    const int ldr = lane >> 2;   // row within 16-row chunk
    const int ldc = lane & 3;    // 8-elem chunk within 32-elem row
    const _Float16* gA0 = A  + (size_t)(m0 + 32*wave + ldr) * 1024 + ldc*8;
    const _Float16* gA1 = gA0 + (size_t)16 * 1024;
    const _Float16* gB0 = Bt + (size_t)(n0 + 32*wave + ldr) * 1024 + ldc*8;
    const _Float16* gB1 = gB0 + (size_t)16 * 1024;
    _Float16* lA0 = &As[0][0] + wave*1024 + lane*8;
    _Float16* lA1 = lA0 + 512;
    _Float16* lB0 = &Bs[0][0] + wave*1024 + lane*8;
    _Float16* lB1 = lB0 + 512;

    // fragment indexing (verified layouts: A row=lane&15, k=(lane>>4)*8+j;
    // C/D col=lane&15, row=(lane>>4)*4+reg)
    const int fr = lane & 15;
    const int fc = lane >> 4;
    const int wm = (wave >> 1) * 64;
    const int wn = (wave & 1) * 64;

    floatx4 acc[4][4];
    #pragma unroll
    for (int i = 0; i < 4; ++i)
        #pragma unroll
        for (int j = 0; j < 4; ++j)
            acc[i][j] = (floatx4){0.f, 0.f, 0.f, 0.f};

    for (int kt = 0; kt < 32; ++kt) {
        __builtin_amdgcn_global_load_lds(GLB_CAST(gA0), LDS_CAST(lA0), 16, 0, 0);
        __builtin_amdgcn_global_load_lds(GLB_CAST(gA1), LDS_CAST(lA1), 16, 0, 0);
        __builtin_amdgcn_global_load_lds(GLB_CAST(gB0), LDS_CAST(lB0), 16, 0, 0);
        __builtin_amdgcn_global_load_lds(GLB_CAST(gB1), LDS_CAST(lB1), 16, 0, 0);
        gA0 += 32; gA1 += 32; gB0 += 32; gB1 += 32;
        __syncthreads();
        half8_t af[4], bf[4];
        #pragma unroll
        for (int i = 0; i < 4; ++i) af[i] = *(const half8_t*)&As[wm + i*16 + fr][fc*8];
        #pragma unroll
        for (int i = 0; i < 4; ++i) bf[i] = *(const half8_t*)&Bs[wn + i*16 + fr][fc*8];
        #pragma unroll
        for (int mi = 0; mi < 4; ++mi)
            #pragma unroll
            for (int ni = 0; ni < 4; ++ni)
                acc[mi][ni] = __builtin_amdgcn_mfma_f32_16x16x32_f16(af[mi], bf[ni], acc[mi][ni], 0, 0, 0);
        __syncthreads();
    }

    #pragma unroll
    for (int mi = 0; mi < 4; ++mi) {
        #pragma unroll
        for (int r = 0; r < 4; ++r) {
            int row = m0 + wm + mi*16 + fc*4 + r;
            _Float16* cp = C + (size_t)row * 2048 + n0 + wn + fr;
            #pragma unroll
            for (int ni = 0; ni < 4; ++ni)
                cp[ni*16] = (_Float16)acc[mi][ni][r];
        }
    }
}

// ---------------------------------------------------------------------------
// Kernel 4: expectations from S.  For qubit q (bit m=1<<(9-q)):
//   cross = sum_{k: k&m==0} conj(S[k]) * S[k|m];  ex=2Re, ey=2Im,
//   ez = sum (k&m ? -|S[k]|^2 : +|S[k]|^2)
// ---------------------------------------------------------------------------
__global__ __launch_bounds__(256) void expect_kernel(const _Float16* __restrict__ Sh,
                                                     float* __restrict__ out)
{
    __shared__ float2 sb[1024];
    __shared__ float part[4][30];
    const int tid = threadIdx.x;
    const int b = blockIdx.x;
    half8_t v = ((const half8_t*)(Sh + (size_t)b * 2048))[tid];
    #pragma unroll
    for (int i = 0; i < 4; ++i)
        sb[tid*4 + i] = make_float2((float)v[2*i], (float)v[2*i + 1]);
    __syncthreads();

    float cr[10], ci[10], cz[10];
    #pragma unroll
    for (int q = 0; q < 10; ++q) { cr[q] = 0.f; ci[q] = 0.f; cz[q] = 0.f; }
    #pragma unroll
    for (int it = 0; it < 4; ++it) {
        int k = tid + it*256;
        float2 a = sb[k];
        float p2 = a.x*a.x + a.y*a.y;
        #pragma unroll
        for (int q = 0; q < 10; ++q) {
            int m = 1 << (9 - q);
            if (k & m) {
                cz[q] -= p2;
            } else {
                cz[q] += p2;
                float2 bb = sb[k | m];
                cr[q] += a.x*bb.x + a.y*bb.y;
                ci[q] += a.x*bb.y - a.y*bb.x;
            }
        }
    }
    #pragma unroll
    for (int q = 0; q < 10; ++q) {
        #pragma unroll
        for (int off = 32; off; off >>= 1) {
            cr[q] += __shfl_down(cr[q], off);
            ci[q] += __shfl_down(ci[q], off);
            cz[q] += __shfl_down(cz[q], off);
        }
    }
    const int wv = tid >> 6, ln = tid & 63;
    if (ln == 0) {
        #pragma unroll
        for (int q = 0; q < 10; ++q) {
            part[wv][q]      = cr[q];
            part[wv][10 + q] = ci[q];
            part[wv][20 + q] = cz[q];
        }
    }
    __syncthreads();
    if (tid < 30) {
        float s2 = part[0][tid] + part[1][tid] + part[2][tid] + part[3][tid];
        if (tid < 20) s2 *= 2.0f;
        out[(size_t)b * 30 + tid] = s2;
    }
}

// ---------------------------------------------------------------------------
extern "C" void kernel_launch(void* const* d_in, const int* in_sizes, int n_in,
                              void* d_out, int out_size, void* d_ws, size_t ws_size,
                              hipStream_t stream) {
    const float* x = (const float*)d_in[0];   // [8192][1024]
    const float* w = (const float*)d_in[1];   // [10][4]
    float* out = (float*)d_out;               // [8192][30]
    char* ws = (char*)d_ws;
    // workspace layout (56 MB total):
    _Float16* Wh = (_Float16*)(ws);                         //  4 MB [1024][2048]
    _Float16* Bt = (_Float16*)(ws + ((size_t)4  << 20));    //  4 MB [2048][1024]
    _Float16* Xh = (_Float16*)(ws + ((size_t)8  << 20));    // 16 MB [8192][1024]
    _Float16* Sh = (_Float16*)(ws + ((size_t)24 << 20));    // 32 MB [8192][2048]

    build_w_kernel<<<1024, 256, 0, stream>>>(w, Wh);
    transpose_kernel<<<dim3(64, 32), dim3(32, 8), 0, stream>>>(Wh, Bt);
    normalize_kernel<<<8192, 256, 0, stream>>>(x, Xh);
    gemm_kernel<<<dim3(16, 64), 256, 0, stream>>>(Xh, Bt, Sh);
    expect_kernel<<<8192, 256, 0, stream>>>(Sh, out);
}

// Round 2
// 204.142 us; speedup vs baseline: 1.1408x; 1.1408x over previous
//
#include <hip/hip_runtime.h>

// ---------------------------------------------------------------------------
// QuantumQKGenerator: out[b, 0..9]=<X_q>, [10..19]=<Y_q>, [20..29]=<Z_q> of
// state S = QFT * U_circuit * normalize(x[b]).  Since x is real and the
// circuit+QFT is a fixed unitary W (depends only on the 40 weights), we:
//   1) build W rows by basis-state simulation + FFT  (cheap)
//   2) transpose to K-contiguous layout for MFMA
//   3) S = Xn @ W  as one fp16 MFMA GEMM  M=8192 N=2048(re/im) K=1024
//   4) reduce expectations from S (register-resident pair products,
//      swizzled-LDS cross-lane chunks, LDS-transpose reduction)
// ---------------------------------------------------------------------------

typedef _Float16 half8_t __attribute__((ext_vector_type(8)));
typedef _Float16 half4_t __attribute__((ext_vector_type(4)));
typedef float floatx4 __attribute__((ext_vector_type(4)));

#define GLB_CAST(p) ((const __attribute__((address_space(1))) void*)(p))
#define LDS_CAST(p) ((__attribute__((address_space(3))) void*)(p))

// ---------------------------------------------------------------------------
// Kernel 1: simulate circuit on basis state |j>, then QFT via radix-2 FFT.
// Writes Wh[j][2k]=Re W[j][k], Wh[j][2k+1]=Im W[j][k]  (fp16, [1024][2048]).
// Wire q <-> bit position (9-q)  (wire 0 = MSB).
// ---------------------------------------------------------------------------
__global__ __launch_bounds__(256) void build_w_kernel(const float* __restrict__ w,
                                                      _Float16* __restrict__ Wh)
{
    __shared__ float sr[1024];
    __shared__ float si[1024];
    const int tid = threadIdx.x;
    const int jb  = blockIdx.x;

    for (int i = tid; i < 1024; i += 256) { sr[i] = (i == jb) ? 1.0f : 0.0f; si[i] = 0.0f; }
    __syncthreads();

    // layers: 0=RX(w0), 1=RY(w1), 2=RZ(w2), [CNOT ring], 3=RY(w3)
    for (int layer = 0; layer < 4; ++layer) {
        if (layer == 3) {
            // CNOT ring: control q, target (q+1)%10
            for (int q = 0; q < 10; ++q) {
                int mc = 1 << (9 - q);
                int mt = 1 << (9 - ((q + 1) % 10));
                for (int p = tid; p < 512; p += 256) {
                    int i0 = ((p & ~(mt - 1)) << 1) | (p & (mt - 1)); // target bit = 0
                    if (i0 & mc) {
                        int i1 = i0 | mt;
                        float tr = sr[i0]; sr[i0] = sr[i1]; sr[i1] = tr;
                        float ti = si[i0]; si[i0] = si[i1]; si[i1] = ti;
                    }
                }
                __syncthreads();
            }
        }
        int wi = (layer == 3) ? 3 : layer;
        for (int q = 0; q < 10; ++q) {
            float t = w[q * 4 + wi] * 0.5f;
            float c = cosf(t), s = sinf(t);
            float u00r, u00i, u01r, u01i, u10r, u10i, u11r, u11i;
            if (layer == 0) {        // RX = [[c, -i s],[-i s, c]]
                u00r=c; u00i=0; u01r=0; u01i=-s; u10r=0; u10i=-s; u11r=c; u11i=0;
            } else if (layer == 2) { // RZ = [[e^{-it/2},0],[0,e^{+it/2}]]
                u00r=c; u00i=-s; u01r=0; u01i=0; u10r=0; u10i=0; u11r=c; u11i=s;
            } else {                 // RY = [[c,-s],[s,c]]
                u00r=c; u00i=0; u01r=-s; u01i=0; u10r=s; u10i=0; u11r=c; u11i=0;
            }
            int m = 1 << (9 - q);
            for (int p = tid; p < 512; p += 256) {
                int i0 = ((p & ~(m - 1)) << 1) | (p & (m - 1));
                int i1 = i0 | m;
                float ar = sr[i0], ai = si[i0], br = sr[i1], bi = si[i1];
                sr[i0] = u00r*ar - u00i*ai + u01r*br - u01i*bi;
                si[i0] = u00r*ai + u00i*ar + u01r*bi + u01i*br;
                sr[i1] = u10r*ar - u10i*ai + u11r*br - u11i*bi;
                si[i1] = u10r*ai + u10i*ar + u11r*bi + u11i*br;
            }
            __syncthreads();
        }
    }

    // QFT_MAT[j,k] = exp(+2*pi*i*j*k/1024)/32  -> unnormalized inverse-sign
    // radix-2 DIT FFT (bit-reverse, +i twiddles), then * 1/32.
    for (int i = tid; i < 1024; i += 256) {
        int r = (int)(__brev((unsigned)i) >> 22);
        if (r > i) {
            float tr = sr[i]; sr[i] = sr[r]; sr[r] = tr;
            float ti = si[i]; si[i] = si[r]; si[r] = ti;
        }
    }
    __syncthreads();
    for (int st = 1; st <= 10; ++st) {
        int hf = 1 << (st - 1);
        float astep = 6.28318530717958647f / (float)(1 << st);
        for (int p = tid; p < 512; p += 256) {
            int j2 = p & (hf - 1);
            int i0 = ((p >> (st - 1)) << st) | j2;
            int i1 = i0 + hf;
            float ang = astep * (float)j2;
            float sw, cw;
            __sincosf(ang, &sw, &cw);
            float br2 = sr[i1], bi2 = si[i1];
            float tr = cw*br2 - sw*bi2;
            float ti = cw*bi2 + sw*br2;
            float ur = sr[i0], ui = si[i0];
            sr[i0] = ur + tr; si[i0] = ui + ti;
            sr[i1] = ur - tr; si[i1] = ui - ti;
        }
        __syncthreads();
    }
    for (int k = tid; k < 1024; k += 256) {
        Wh[(size_t)jb * 2048 + 2*k]     = (_Float16)(sr[k] * 0.03125f);
        Wh[(size_t)jb * 2048 + 2*k + 1] = (_Float16)(si[k] * 0.03125f);
    }
}

// ---------------------------------------------------------------------------
// Kernel 1b: Bt[n][j] = Wh[j][n]   ([2048][1024] fp16, K-contiguous rows)
// ---------------------------------------------------------------------------
__global__ __launch_bounds__(256) void transpose_kernel(const _Float16* __restrict__ Wh,
                                                        _Float16* __restrict__ Bt)
{
    __shared__ _Float16 tile[32][33];
    const int bx = blockIdx.x;   // n tile (64)
    const int by = blockIdx.y;   // j tile (32)
    const int tx = threadIdx.x;  // 32
    const int ty = threadIdx.y;  // 8
    #pragma unroll
    for (int i = 0; i < 4; ++i) {
        int r = ty + 8*i;
        tile[r][tx] = Wh[(size_t)(by*32 + r) * 2048 + bx*32 + tx];
    }
    __syncthreads();
    #pragma unroll
    for (int i = 0; i < 4; ++i) {
        int r = ty + 8*i;
        Bt[(size_t)(bx*32 + r) * 1024 + by*32 + tx] = tile[tx][r];
    }
}

// ---------------------------------------------------------------------------
// Kernel 2: row-normalize x (fp32) and store fp16  Xh[8192][1024]
// ---------------------------------------------------------------------------
__global__ __launch_bounds__(256) void normalize_kernel(const float* __restrict__ x,
                                                        _Float16* __restrict__ Xh)
{
    __shared__ float wsum[4];
    const int tid = threadIdx.x;
    const int b = blockIdx.x;
    float4 v = ((const float4*)(x + (size_t)b * 1024))[tid];
    float ss = v.x*v.x + v.y*v.y + v.z*v.z + v.w*v.w;
    #pragma unroll
    for (int off = 32; off; off >>= 1) ss += __shfl_down(ss, off);
    if ((tid & 63) == 0) wsum[tid >> 6] = ss;
    __syncthreads();
    float scale = 1.0f / fmaxf(sqrtf(wsum[0] + wsum[1] + wsum[2] + wsum[3]), 1e-8f);
    half4_t h;
    h[0] = (_Float16)(v.x * scale);
    h[1] = (_Float16)(v.y * scale);
    h[2] = (_Float16)(v.z * scale);
    h[3] = (_Float16)(v.w * scale);
    ((half4_t*)(Xh + (size_t)b * 1024))[tid] = h;
}

// ---------------------------------------------------------------------------
// Kernel 3: GEMM  Sh[8192][2048] = Xh[8192][1024] * Bt^T  (fp16 in, fp32 acc,
// fp16 out).  m97 structure: 128x128 tile, BK=32, global_load_lds width 16,
// 16x16x32 f16 MFMA, 4 waves in 2x2, 4x4 fragments each.
// ---------------------------------------------------------------------------
__global__ __launch_bounds__(256, 2) void gemm_kernel(const _Float16* __restrict__ A,
                                                      const _Float16* __restrict__ Bt,
                                                      _Float16* __restrict__ C)
{
    __shared__ __align__(16) _Float16 As[128][32];
    __shared__ __align__(16) _Float16 Bs[128][32];
    const int tid  = threadIdx.x;
    const int wave = tid >> 6;
    const int lane = tid & 63;
    const int m0 = blockIdx.y * 128;
    const int n0 = blockIdx.x * 128;

    // staging: wave w loads rows [32w, 32w+32) of each tile; lane l -> slot l*16B
    const int ldr = lane >> 2;   // row within 16-row chunk
    const int ldc = lane & 3;    // 8-elem chunk within 32-elem row
    const _Float16* gA0 = A  + (size_t)(m0 + 32*wave + ldr) * 1024 + ldc*8;
    const _Float16* gA1 = gA0 + (size_t)16 * 1024;
    const _Float16* gB0 = Bt + (size_t)(n0 + 32*wave + ldr) * 1024 + ldc*8;
    const _Float16* gB1 = gB0 + (size_t)16 * 1024;
    _Float16* lA0 = &As[0][0] + wave*1024 + lane*8;
    _Float16* lA1 = lA0 + 512;
    _Float16* lB0 = &Bs[0][0] + wave*1024 + lane*8;
    _Float16* lB1 = lB0 + 512;

    // fragment indexing (verified layouts: A row=lane&15, k=(lane>>4)*8+j;
    // C/D col=lane&15, row=(lane>>4)*4+reg)
    const int fr = lane & 15;
    const int fc = lane >> 4;
    const int wm = (wave >> 1) * 64;
    const int wn = (wave & 1) * 64;

    floatx4 acc[4][4];
    #pragma unroll
    for (int i = 0; i < 4; ++i)
        #pragma unroll
        for (int j = 0; j < 4; ++j)
            acc[i][j] = (floatx4){0.f, 0.f, 0.f, 0.f};

    for (int kt = 0; kt < 32; ++kt) {
        __builtin_amdgcn_global_load_lds(GLB_CAST(gA0), LDS_CAST(lA0), 16, 0, 0);
        __builtin_amdgcn_global_load_lds(GLB_CAST(gA1), LDS_CAST(lA1), 16, 0, 0);
        __builtin_amdgcn_global_load_lds(GLB_CAST(gB0), LDS_CAST(lB0), 16, 0, 0);
        __builtin_amdgcn_global_load_lds(GLB_CAST(gB1), LDS_CAST(lB1), 16, 0, 0);
        gA0 += 32; gA1 += 32; gB0 += 32; gB1 += 32;
        __syncthreads();
        half8_t af[4], bf[4];
        #pragma unroll
        for (int i = 0; i < 4; ++i) af[i] = *(const half8_t*)&As[wm + i*16 + fr][fc*8];
        #pragma unroll
        for (int i = 0; i < 4; ++i) bf[i] = *(const half8_t*)&Bs[wn + i*16 + fr][fc*8];
        #pragma unroll
        for (int mi = 0; mi < 4; ++mi)
            #pragma unroll
            for (int ni = 0; ni < 4; ++ni)
                acc[mi][ni] = __builtin_amdgcn_mfma_f32_16x16x32_f16(af[mi], bf[ni], acc[mi][ni], 0, 0, 0);
        __syncthreads();
    }

    #pragma unroll
    for (int mi = 0; mi < 4; ++mi) {
        #pragma unroll
        for (int r = 0; r < 4; ++r) {
            int row = m0 + wm + mi*16 + fc*4 + r;
            _Float16* cp = C + (size_t)row * 2048 + n0 + wn + fr;
            #pragma unroll
            for (int ni = 0; ni < 4; ++ni)
                cp[ni*16] = (_Float16)acc[mi][ni][r];
        }
    }
}

// ---------------------------------------------------------------------------
// Kernel 4: expectations from S.  One WAVE per batch row; lane l owns the 16
// complex amps k = l*16 + i in registers.
//   k-bits 0..3  (qubits 9..6): intra-lane pairs, pure register math.
//   k-bits 4..9  (qubits 5..0): lane-XOR {1,2,4,8,16,32}; partner chunk
//     fetched from a 16B-XOR-swizzled wave-private LDS copy of the row
//     (4 ds_read_b128/lane/qubit, work split between the pair's two lanes).
//   Reduction: LDS transpose (stride 33, conflict-free) + 1 shuffle — NOT
//   30x6 shuffles.  This cuts DS instrs/row ~900 -> ~95.
// ---------------------------------------------------------------------------
__global__ __launch_bounds__(128) void expect_kernel(const _Float16* __restrict__ Sh,
                                                     float* __restrict__ out)
{
    __shared__ __align__(16) float2 sb[2][1024];   // swizzled row, per wave (8KB each)
    __shared__ float pt[2][64 * 33];               // reduction partials, per wave
    const int tid = threadIdx.x;
    const int w = tid >> 6, l = tid & 63;
    const int row = blockIdx.x * 2 + w;

    // ---- load own 16 complex amps (64B contiguous per lane) -> registers
    const _Float16* src = Sh + (size_t)row * 2048 + l * 32;
    float2 c[16];
    #pragma unroll
    for (int t = 0; t < 4; ++t) {
        half8_t v = ((const half8_t*)src)[t];
        #pragma unroll
        for (int u = 0; u < 4; ++u)
            c[t*4 + u] = make_float2((float)v[2*u], (float)v[2*u + 1]);
    }

    // ---- stage to swizzled LDS: unit j (2 complex) at slot l*8 + (j ^ (l&7))
    float2* sbw = sb[w];
    #pragma unroll
    for (int j = 0; j < 8; ++j) {
        int su = l*8 + (j ^ (l & 7));
        ((float4*)sbw)[su] = make_float4(c[2*j].x, c[2*j].y, c[2*j+1].x, c[2*j+1].y);
    }

    // ---- register-only work while staging lands
    float p2[16];
    float P2s = 0.f;
    #pragma unroll
    for (int i = 0; i < 16; ++i) {
        p2[i] = c[i].x*c[i].x + c[i].y*c[i].y;
        P2s += p2[i];
    }
    float cr[10], ci[10], cz[10];
    #pragma unroll
    for (int q = 0; q < 10; ++q) { cr[q] = 0.f; ci[q] = 0.f; cz[q] = 0.f; }

    // intra-lane qubits: k-bit p = 0..3  ->  q = 9-p
    #pragma unroll
    for (int p = 0; p < 4; ++p) {
        const int m = 1 << p;
        const int q = 9 - p;
        #pragma unroll
        for (int i = 0; i < 16; ++i) {
            if (i & m) continue;
            const int j = i | m;
            cr[q] += c[i].x*c[j].x + c[i].y*c[j].y;
            ci[q] += c[i].x*c[j].y - c[i].y*c[j].x;
            cz[q] += p2[i] - p2[j];
        }
    }

    __syncthreads();   // swizzled row visible

    // cross-lane qubits: lane-bit e (k-bit 4+e) -> q = 5-e
    #pragma unroll
    for (int e = 0; e < 6; ++e) {
        const int q = 5 - e;
        const int part = l ^ (1 << e);
        const int mybit = (l >> e) & 1;
        const float sgn = mybit ? -1.f : 1.f;
        const int j0 = mybit ? 4 : 0;   // my/partner unit range for my half of i
        float rr = 0.f, ii = 0.f;
        #pragma unroll
        for (int j = 0; j < 4; ++j) {
            const int ju = j0 + j;
            const int su = part*8 + (ju ^ (part & 7));
            float4 f = ((const float4*)sbw)[su];
            float2 m0 = c[2*ju], m1 = c[2*ju + 1];
            rr += m0.x*f.x + m0.y*f.y;
            ii += m0.x*f.y - m0.y*f.x;
            rr += m1.x*f.z + m1.y*f.w;
            ii += m1.x*f.w - m1.y*f.z;
        }
        cr[q] += rr;
        ci[q] += sgn * ii;
        cz[q] += sgn * P2s;
    }

    // ---- reduction: transpose through LDS (stride 33 => conflict-free)
    float* pw = pt[w];
    #pragma unroll
    for (int q = 0; q < 10; ++q) {
        pw[l*33 + q]      = cr[q];
        pw[l*33 + 10 + q] = ci[q];
        pw[l*33 + 20 + q] = cz[q];
    }
    __syncthreads();

    if (l < 60) {
        const int o = (l < 30) ? l : l - 30;
        const int h = (l < 30) ? 0 : 32;
        float s = 0.f;
        #pragma unroll
        for (int jj = 0; jj < 32; ++jj)
            s += pw[(h + jj)*33 + o];
        float s2 = __shfl(s, (l < 30) ? (l + 30) : (l - 30));
        if (l < 30) {
            float v = s + s2;
            if (o < 20) v *= 2.0f;
            out[(size_t)row * 30 + o] = v;
        }
    }
}

// ---------------------------------------------------------------------------
extern "C" void kernel_launch(void* const* d_in, const int* in_sizes, int n_in,
                              void* d_out, int out_size, void* d_ws, size_t ws_size,
                              hipStream_t stream) {
    const float* x = (const float*)d_in[0];   // [8192][1024]
    const float* w = (const float*)d_in[1];   // [10][4]
    float* out = (float*)d_out;               // [8192][30]
    char* ws = (char*)d_ws;
    // workspace layout (56 MB total):
    _Float16* Wh = (_Float16*)(ws);                         //  4 MB [1024][2048]
    _Float16* Bt = (_Float16*)(ws + ((size_t)4  << 20));    //  4 MB [2048][1024]
    _Float16* Xh = (_Float16*)(ws + ((size_t)8  << 20));    // 16 MB [8192][1024]
    _Float16* Sh = (_Float16*)(ws + ((size_t)24 << 20));    // 32 MB [8192][2048]

    build_w_kernel<<<1024, 256, 0, stream>>>(w, Wh);
    transpose_kernel<<<dim3(64, 32), dim3(32, 8), 0, stream>>>(Wh, Bt);
    normalize_kernel<<<8192, 256, 0, stream>>>(x, Xh);
    gemm_kernel<<<dim3(16, 64), 256, 0, stream>>>(Xh, Bt, Sh);
    expect_kernel<<<4096, 128, 0, stream>>>(Sh, out);
}

// Round 3
// 199.585 us; speedup vs baseline: 1.1669x; 1.0228x over previous
//
#include <hip/hip_runtime.h>

// ---------------------------------------------------------------------------
// QuantumQKGenerator: out[b, 0..9]=<X_q>, [10..19]=<Y_q>, [20..29]=<Z_q> of
// state S = QFT * U_circuit * normalize(x[b]).  Since x is real and the
// circuit+QFT is a fixed unitary W (depends only on the 40 weights), we:
//   1) prep: build W rows by basis-state sim + FFT  AND  normalize x -> fp16
//      (independent works fused into one dispatch for overlap)
//   2) transpose W to K-contiguous layout for MFMA
//   3) S = Xn @ W  as one fp16 MFMA GEMM  M=8192 N=2048(re/im) K=1024
//      (BK=64, XOR-swizzled LDS -> conflict-free ds_read_b128)
//   4) expect: per-wave row reduction, 17KB LDS, zero barriers
// ---------------------------------------------------------------------------

typedef _Float16 half8_t __attribute__((ext_vector_type(8)));
typedef _Float16 half4_t __attribute__((ext_vector_type(4)));
typedef float floatx4 __attribute__((ext_vector_type(4)));

#define GLB_CAST(p) ((const __attribute__((address_space(1))) void*)(p))
#define LDS_CAST(p) ((__attribute__((address_space(3))) void*)(p))

// ---------------------------------------------------------------------------
// Kernel 1: blocks [0,1024): simulate circuit on basis |jb>, FFT, emit W row.
//           blocks [1024,9216): row-normalize x -> fp16 Xh.
// Wire q <-> bit position (9-q)  (wire 0 = MSB).
// ---------------------------------------------------------------------------
__global__ __launch_bounds__(256) void prep_kernel(const float* __restrict__ w,
                                                   const float* __restrict__ x,
                                                   _Float16* __restrict__ Wh,
                                                   _Float16* __restrict__ Xh)
{
    __shared__ float smem[2048 + 88];   // sr[1024] | si[1024] | wc[40] | wsn[40] | wsum[4]
    const int tid = threadIdx.x;

    if (blockIdx.x >= 1024) {
        // ---------------- normalize path ----------------
        float* wsum = smem;
        const int b = blockIdx.x - 1024;
        float4 v = ((const float4*)(x + (size_t)b * 1024))[tid];
        float ss = v.x*v.x + v.y*v.y + v.z*v.z + v.w*v.w;
        #pragma unroll
        for (int off = 32; off; off >>= 1) ss += __shfl_down(ss, off);
        if ((tid & 63) == 0) wsum[tid >> 6] = ss;
        __syncthreads();
        float scale = 1.0f / fmaxf(sqrtf(wsum[0] + wsum[1] + wsum[2] + wsum[3]), 1e-8f);
        half4_t h;
        h[0] = (_Float16)(v.x * scale);
        h[1] = (_Float16)(v.y * scale);
        h[2] = (_Float16)(v.z * scale);
        h[3] = (_Float16)(v.w * scale);
        ((half4_t*)(Xh + (size_t)b * 1024))[tid] = h;
        return;
    }

    // ---------------- build_w path ----------------
    float* sr  = smem;
    float* si  = smem + 1024;
    float* wc  = smem + 2048;
    float* wsn = smem + 2088;
    const int jb = blockIdx.x;

    if (tid < 40) {
        float t = w[tid] * 0.5f;
        wc[tid]  = cosf(t);
        wsn[tid] = sinf(t);
    }
    for (int i = tid; i < 1024; i += 256) { sr[i] = (i == jb) ? 1.0f : 0.0f; si[i] = 0.0f; }
    __syncthreads();

    // layers: 0=RX(w0), 1=RY(w1), 2=RZ(w2), [CNOT ring], 3=RY(w3)
    for (int layer = 0; layer < 4; ++layer) {
        if (layer == 3) {
            // CNOT ring: control q, target (q+1)%10
            for (int q = 0; q < 10; ++q) {
                int mc = 1 << (9 - q);
                int mt = 1 << (9 - ((q + 1) % 10));
                for (int p = tid; p < 512; p += 256) {
                    int i0 = ((p & ~(mt - 1)) << 1) | (p & (mt - 1)); // target bit = 0
                    if (i0 & mc) {
                        int i1 = i0 | mt;
                        float tr = sr[i0]; sr[i0] = sr[i1]; sr[i1] = tr;
                        float ti = si[i0]; si[i0] = si[i1]; si[i1] = ti;
                    }
                }
                __syncthreads();
            }
        }
        int wi = (layer == 3) ? 3 : layer;
        for (int q = 0; q < 10; ++q) {
            float c = wc[q * 4 + wi], s = wsn[q * 4 + wi];
            float u00r, u00i, u01r, u01i, u10r, u10i, u11r, u11i;
            if (layer == 0) {        // RX = [[c, -i s],[-i s, c]]
                u00r=c; u00i=0; u01r=0; u01i=-s; u10r=0; u10i=-s; u11r=c; u11i=0;
            } else if (layer == 2) { // RZ = [[e^{-it/2},0],[0,e^{+it/2}]]
                u00r=c; u00i=-s; u01r=0; u01i=0; u10r=0; u10i=0; u11r=c; u11i=s;
            } else {                 // RY = [[c,-s],[s,c]]
                u00r=c; u00i=0; u01r=-s; u01i=0; u10r=s; u10i=0; u11r=c; u11i=0;
            }
            int m = 1 << (9 - q);
            for (int p = tid; p < 512; p += 256) {
                int i0 = ((p & ~(m - 1)) << 1) | (p & (m - 1));
                int i1 = i0 | m;
                float ar = sr[i0], ai = si[i0], br = sr[i1], bi = si[i1];
                sr[i0] = u00r*ar - u00i*ai + u01r*br - u01i*bi;
                si[i0] = u00r*ai + u00i*ar + u01r*bi + u01i*br;
                sr[i1] = u10r*ar - u10i*ai + u11r*br - u11i*bi;
                si[i1] = u10r*ai + u10i*ar + u11r*bi + u11i*br;
            }
            __syncthreads();
        }
    }

    // QFT_MAT[j,k] = exp(+2*pi*i*j*k/1024)/32 -> radix-2 DIT FFT (+i twiddles)
    for (int i = tid; i < 1024; i += 256) {
        int r = (int)(__brev((unsigned)i) >> 22);
        if (r > i) {
            float tr = sr[i]; sr[i] = sr[r]; sr[r] = tr;
            float ti = si[i]; si[i] = si[r]; si[r] = ti;
        }
    }
    __syncthreads();
    for (int st = 1; st <= 10; ++st) {
        int hf = 1 << (st - 1);
        float astep = 6.28318530717958647f / (float)(1 << st);
        for (int p = tid; p < 512; p += 256) {
            int j2 = p & (hf - 1);
            int i0 = ((p >> (st - 1)) << st) | j2;
            int i1 = i0 + hf;
            float ang = astep * (float)j2;
            float sw, cw;
            __sincosf(ang, &sw, &cw);
            float br2 = sr[i1], bi2 = si[i1];
            float tr = cw*br2 - sw*bi2;
            float ti = cw*bi2 + sw*br2;
            float ur = sr[i0], ui = si[i0];
            sr[i0] = ur + tr; si[i0] = ui + ti;
            sr[i1] = ur - tr; si[i1] = ui - ti;
        }
        __syncthreads();
    }
    for (int k = tid; k < 1024; k += 256) {
        Wh[(size_t)jb * 2048 + 2*k]     = (_Float16)(sr[k] * 0.03125f);
        Wh[(size_t)jb * 2048 + 2*k + 1] = (_Float16)(si[k] * 0.03125f);
    }
}

// ---------------------------------------------------------------------------
// Kernel 1b: Bt[n][j] = Wh[j][n]   ([2048][1024] fp16, K-contiguous rows)
// ---------------------------------------------------------------------------
__global__ __launch_bounds__(256) void transpose_kernel(const _Float16* __restrict__ Wh,
                                                        _Float16* __restrict__ Bt)
{
    __shared__ _Float16 tile[32][33];
    const int bx = blockIdx.x;   // n tile (64)
    const int by = blockIdx.y;   // j tile (32)
    const int tx = threadIdx.x;  // 32
    const int ty = threadIdx.y;  // 8
    #pragma unroll
    for (int i = 0; i < 4; ++i) {
        int r = ty + 8*i;
        tile[r][tx] = Wh[(size_t)(by*32 + r) * 2048 + bx*32 + tx];
    }
    __syncthreads();
    #pragma unroll
    for (int i = 0; i < 4; ++i) {
        int r = ty + 8*i;
        Bt[(size_t)(bx*32 + r) * 1024 + by*32 + tx] = tile[tx][r];
    }
}

// ---------------------------------------------------------------------------
// Kernel 2: GEMM  Sh[8192][2048] = Xh[8192][1024] * Bt^T  (fp16 in, fp32 acc,
// fp16 out).  128x128 tile, BK=64 (16 k-iters, half the barriers of BK=32),
// global_load_lds width 16.  LDS chunk index XOR-swizzled by row&7 so the
// fragment ds_read_b128s are 2-way (free) instead of bank-serialized; the
// swizzle is applied on the GLOBAL address side to keep the wave-uniform
// base + 16B*lane LDS layout global_load_lds requires.
// ---------------------------------------------------------------------------
__global__ __launch_bounds__(256, 2) void gemm_kernel(const _Float16* __restrict__ A,
                                                      const _Float16* __restrict__ Bt,
                                                      _Float16* __restrict__ C)
{
    __shared__ __align__(16) _Float16 As[128][64];
    __shared__ __align__(16) _Float16 Bs[128][64];
    const int tid  = threadIdx.x;
    const int wave = tid >> 6;
    const int lane = tid & 63;
    const int m0 = blockIdx.y * 128;
    const int n0 = blockIdx.x * 128;

    // staging: wave w, instr t covers rows 32w+8t .. 32w+8t+7.
    // lane l -> row offset (l>>3), global k-chunk ((l&7) ^ (l>>3))  [swizzle]
    const int srow = lane >> 3;                 // 0..7
    const int schk = (lane & 7) ^ srow;         // swizzled chunk
    const _Float16* gA = A  + (size_t)(m0 + 32*wave + srow) * 1024 + schk * 8;
    const _Float16* gB = Bt + (size_t)(n0 + 32*wave + srow) * 1024 + schk * 8;
    _Float16* lA = &As[0][0] + wave*2048 + lane*8;
    _Float16* lB = &Bs[0][0] + wave*2048 + lane*8;

    // fragment indexing (verified layouts: A row=lane&15, k=(lane>>4)*8+j;
    // C/D col=lane&15, row=(lane>>4)*4+reg)
    const int fr = lane & 15;
    const int fc = lane >> 4;
    const int sx = fr & 7;          // de-swizzle constant for fragment reads
    const int wm = (wave >> 1) * 64;
    const int wn = (wave & 1) * 64;

    floatx4 acc[4][4];
    #pragma unroll
    for (int i = 0; i < 4; ++i)
        #pragma unroll
        for (int j = 0; j < 4; ++j)
            acc[i][j] = (floatx4){0.f, 0.f, 0.f, 0.f};

    for (int kt = 0; kt < 16; ++kt) {
        #pragma unroll
        for (int t = 0; t < 4; ++t) {
            __builtin_amdgcn_global_load_lds(GLB_CAST(gA + (size_t)t*8*1024), LDS_CAST(lA + t*512), 16, 0, 0);
            __builtin_amdgcn_global_load_lds(GLB_CAST(gB + (size_t)t*8*1024), LDS_CAST(lB + t*512), 16, 0, 0);
        }
        gA += 64; gB += 64;
        __syncthreads();
        #pragma unroll
        for (int kh = 0; kh < 2; ++kh) {
            half8_t af[4], bf[4];
            #pragma unroll
            for (int i = 0; i < 4; ++i)
                af[i] = *(const half8_t*)&As[wm + i*16 + fr][((kh*4 + fc) ^ sx) * 8];
            #pragma unroll
            for (int i = 0; i < 4; ++i)
                bf[i] = *(const half8_t*)&Bs[wn + i*16 + fr][((kh*4 + fc) ^ sx) * 8];
            #pragma unroll
            for (int mi = 0; mi < 4; ++mi)
                #pragma unroll
                for (int ni = 0; ni < 4; ++ni)
                    acc[mi][ni] = __builtin_amdgcn_mfma_f32_16x16x32_f16(af[mi], bf[ni], acc[mi][ni], 0, 0, 0);
        }
        __syncthreads();
    }

    #pragma unroll
    for (int mi = 0; mi < 4; ++mi) {
        #pragma unroll
        for (int r = 0; r < 4; ++r) {
            int row = m0 + wm + mi*16 + fc*4 + r;
            _Float16* cp = C + (size_t)row * 2048 + n0 + wn + fr;
            #pragma unroll
            for (int ni = 0; ni < 4; ++ni)
                cp[ni*16] = (_Float16)acc[mi][ni][r];
        }
    }
}

// ---------------------------------------------------------------------------
// Kernel 3: expectations from S.  One WAVE per batch row; lane l owns the 16
// complex amps k = l*16 + i in registers.
//   k-bits 0..3  (qubits 9..6): intra-lane pairs, pure register math.
//   k-bits 4..9  (qubits 5..0): lane-XOR {1,2,4,8,16,32}; partner chunk
//     fetched from a 16B-XOR-swizzled wave-private LDS copy of the row.
//   Reduction: LDS transpose (stride 33, 2-way=free) reusing the SAME LDS
//     region (row buffer is dead by then).  Waves are fully independent:
//     NO __syncthreads anywhere -> 17 KB LDS, 9 blocks/CU.
// ---------------------------------------------------------------------------
__global__ __launch_bounds__(128) void expect_kernel(const _Float16* __restrict__ Sh,
                                                     float* __restrict__ out)
{
    __shared__ __align__(16) float buf[2][2176];   // per-wave: row(2048) / pt(2112) alias
    const int tid = threadIdx.x;
    const int w = tid >> 6, l = tid & 63;
    const int row = blockIdx.x * 2 + w;
    float* bw = buf[w];

    // ---- load own 16 complex amps (64B contiguous per lane) -> registers
    const _Float16* src = Sh + (size_t)row * 2048 + l * 32;
    float2 c[16];
    #pragma unroll
    for (int t = 0; t < 4; ++t) {
        half8_t v = ((const half8_t*)src)[t];
        #pragma unroll
        for (int u = 0; u < 4; ++u)
            c[t*4 + u] = make_float2((float)v[2*u], (float)v[2*u + 1]);
    }

    // ---- stage to swizzled LDS: unit j (2 complex) at slot l*8 + (j ^ (l&7))
    #pragma unroll
    for (int j = 0; j < 8; ++j) {
        int su = l*8 + (j ^ (l & 7));
        ((float4*)bw)[su] = make_float4(c[2*j].x, c[2*j].y, c[2*j+1].x, c[2*j+1].y);
    }

    // ---- register-only work while staging lands
    float p2[16];
    float P2s = 0.f;
    #pragma unroll
    for (int i = 0; i < 16; ++i) {
        p2[i] = c[i].x*c[i].x + c[i].y*c[i].y;
        P2s += p2[i];
    }
    float cr[10], ci[10], cz[10];
    #pragma unroll
    for (int q = 0; q < 10; ++q) { cr[q] = 0.f; ci[q] = 0.f; cz[q] = 0.f; }

    // intra-lane qubits: k-bit p = 0..3  ->  q = 9-p
    #pragma unroll
    for (int p = 0; p < 4; ++p) {
        const int m = 1 << p;
        const int q = 9 - p;
        #pragma unroll
        for (int i = 0; i < 16; ++i) {
            if (i & m) continue;
            const int j = i | m;
            cr[q] += c[i].x*c[j].x + c[i].y*c[j].y;
            ci[q] += c[i].x*c[j].y - c[i].y*c[j].x;
            cz[q] += p2[i] - p2[j];
        }
    }

    // cross-lane qubits: lane-bit e (k-bit 4+e) -> q = 5-e
    // (wave-internal LDS ordering: no barrier needed)
    #pragma unroll
    for (int e = 0; e < 6; ++e) {
        const int q = 5 - e;
        const int part = l ^ (1 << e);
        const int mybit = (l >> e) & 1;
        const float sgn = mybit ? -1.f : 1.f;
        const int j0 = mybit ? 4 : 0;   // my half of the pair's units
        float rr = 0.f, ii = 0.f;
        #pragma unroll
        for (int j = 0; j < 4; ++j) {
            const int ju = j0 + j;
            const int su = part*8 + (ju ^ (part & 7));
            float4 f = ((const float4*)bw)[su];
            float2 m0 = c[2*ju], m1 = c[2*ju + 1];
            rr += m0.x*f.x + m0.y*f.y;
            ii += m0.x*f.y - m0.y*f.x;
            rr += m1.x*f.z + m1.y*f.w;
            ii += m1.x*f.w - m1.y*f.z;
        }
        cr[q] += rr;
        ci[q] += sgn * ii;
        cz[q] += sgn * P2s;
    }

    // ---- reduction: transpose through the SAME LDS region (row buffer dead)
    #pragma unroll
    for (int q = 0; q < 10; ++q) {
        bw[l*33 + q]      = cr[q];
        bw[l*33 + 10 + q] = ci[q];
        bw[l*33 + 20 + q] = cz[q];
    }

    if (l < 60) {
        const int o = (l < 30) ? l : l - 30;
        const int h = (l < 30) ? 0 : 32;
        float s = 0.f;
        #pragma unroll
        for (int jj = 0; jj < 32; ++jj)
            s += bw[(h + jj)*33 + o];
        float s2 = __shfl(s, (l < 30) ? (l + 30) : (l - 30));
        if (l < 30) {
            float v = s + s2;
            if (o < 20) v *= 2.0f;
            out[(size_t)row * 30 + o] = v;
        }
    }
}

// ---------------------------------------------------------------------------
extern "C" void kernel_launch(void* const* d_in, const int* in_sizes, int n_in,
                              void* d_out, int out_size, void* d_ws, size_t ws_size,
                              hipStream_t stream) {
    const float* x = (const float*)d_in[0];   // [8192][1024]
    const float* w = (const float*)d_in[1];   // [10][4]
    float* out = (float*)d_out;               // [8192][30]
    char* ws = (char*)d_ws;
    // workspace layout (56 MB total):
    _Float16* Wh = (_Float16*)(ws);                         //  4 MB [1024][2048]
    _Float16* Bt = (_Float16*)(ws + ((size_t)4  << 20));    //  4 MB [2048][1024]
    _Float16* Xh = (_Float16*)(ws + ((size_t)8  << 20));    // 16 MB [8192][1024]
    _Float16* Sh = (_Float16*)(ws + ((size_t)24 << 20));    // 32 MB [8192][2048]

    prep_kernel<<<9216, 256, 0, stream>>>(w, x, Wh, Xh);
    transpose_kernel<<<dim3(64, 32), dim3(32, 8), 0, stream>>>(Wh, Bt);
    gemm_kernel<<<dim3(16, 64), 256, 0, stream>>>(Xh, Bt, Sh);
    expect_kernel<<<4096, 128, 0, stream>>>(Sh, out);
}

// Round 4
// 190.672 us; speedup vs baseline: 1.2214x; 1.0467x over previous
//
#include <hip/hip_runtime.h>

// ---------------------------------------------------------------------------
// QuantumQKGenerator: out[b, 0..9]=<X_q>, [10..19]=<Y_q>, [20..29]=<Z_q> of
// state S = QFT * U_circuit * normalize(x[b]).  Since x is real and the
// circuit+QFT is a fixed unitary W (depends only on the 40 weights), we:
//   1) prep: build W rows by basis-state sim + FFT  AND  normalize x -> fp16
//   2) transpose W to K-contiguous layout for MFMA
//   3) S = Xn @ W  as one fp16 MFMA GEMM  M=8192 N=2048(re/im) K=1024
//   4) expect: per-wave row reduction, 17KB LDS, zero barriers,
//      __launch_bounds__(128,4) -> 128-VGPR budget, NO SPILLS
// ---------------------------------------------------------------------------

typedef _Float16 half8_t __attribute__((ext_vector_type(8)));
typedef _Float16 half4_t __attribute__((ext_vector_type(4)));
typedef float floatx4 __attribute__((ext_vector_type(4)));

#define GLB_CAST(p) ((const __attribute__((address_space(1))) void*)(p))
#define LDS_CAST(p) ((__attribute__((address_space(3))) void*)(p))

// ---------------------------------------------------------------------------
// Kernel 1: blocks [0,1024): simulate circuit on basis |jb>, FFT, emit W row.
//           blocks [1024,9216): row-normalize x -> fp16 Xh.
// Wire q <-> bit position (9-q)  (wire 0 = MSB).
// ---------------------------------------------------------------------------
__global__ __launch_bounds__(256) void prep_kernel(const float* __restrict__ w,
                                                   const float* __restrict__ x,
                                                   _Float16* __restrict__ Wh,
                                                   _Float16* __restrict__ Xh)
{
    __shared__ float smem[2048 + 88];   // sr[1024] | si[1024] | wc[40] | wsn[40] | wsum[4]
    const int tid = threadIdx.x;

    if (blockIdx.x >= 1024) {
        // ---------------- normalize path ----------------
        float* wsum = smem;
        const int b = blockIdx.x - 1024;
        float4 v = ((const float4*)(x + (size_t)b * 1024))[tid];
        float ss = v.x*v.x + v.y*v.y + v.z*v.z + v.w*v.w;
        #pragma unroll
        for (int off = 32; off; off >>= 1) ss += __shfl_down(ss, off);
        if ((tid & 63) == 0) wsum[tid >> 6] = ss;
        __syncthreads();
        float scale = 1.0f / fmaxf(sqrtf(wsum[0] + wsum[1] + wsum[2] + wsum[3]), 1e-8f);
        half4_t h;
        h[0] = (_Float16)(v.x * scale);
        h[1] = (_Float16)(v.y * scale);
        h[2] = (_Float16)(v.z * scale);
        h[3] = (_Float16)(v.w * scale);
        ((half4_t*)(Xh + (size_t)b * 1024))[tid] = h;
        return;
    }

    // ---------------- build_w path ----------------
    float* sr  = smem;
    float* si  = smem + 1024;
    float* wc  = smem + 2048;
    float* wsn = smem + 2088;
    const int jb = blockIdx.x;

    if (tid < 40) {
        float t = w[tid] * 0.5f;
        wc[tid]  = cosf(t);
        wsn[tid] = sinf(t);
    }
    for (int i = tid; i < 1024; i += 256) { sr[i] = (i == jb) ? 1.0f : 0.0f; si[i] = 0.0f; }
    __syncthreads();

    // layers: 0=RX(w0), 1=RY(w1), 2=RZ(w2), [CNOT ring], 3=RY(w3)
    for (int layer = 0; layer < 4; ++layer) {
        if (layer == 3) {
            // CNOT ring: control q, target (q+1)%10
            for (int q = 0; q < 10; ++q) {
                int mc = 1 << (9 - q);
                int mt = 1 << (9 - ((q + 1) % 10));
                for (int p = tid; p < 512; p += 256) {
                    int i0 = ((p & ~(mt - 1)) << 1) | (p & (mt - 1)); // target bit = 0
                    if (i0 & mc) {
                        int i1 = i0 | mt;
                        float tr = sr[i0]; sr[i0] = sr[i1]; sr[i1] = tr;
                        float ti = si[i0]; si[i0] = si[i1]; si[i1] = ti;
                    }
                }
                __syncthreads();
            }
        }
        int wi = (layer == 3) ? 3 : layer;
        for (int q = 0; q < 10; ++q) {
            float c = wc[q * 4 + wi], s = wsn[q * 4 + wi];
            float u00r, u00i, u01r, u01i, u10r, u10i, u11r, u11i;
            if (layer == 0) {        // RX = [[c, -i s],[-i s, c]]
                u00r=c; u00i=0; u01r=0; u01i=-s; u10r=0; u10i=-s; u11r=c; u11i=0;
            } else if (layer == 2) { // RZ = [[e^{-it/2},0],[0,e^{+it/2}]]
                u00r=c; u00i=-s; u01r=0; u01i=0; u10r=0; u10i=0; u11r=c; u11i=s;
            } else {                 // RY = [[c,-s],[s,c]]
                u00r=c; u00i=0; u01r=-s; u01i=0; u10r=s; u10i=0; u11r=c; u11i=0;
            }
            int m = 1 << (9 - q);
            for (int p = tid; p < 512; p += 256) {
                int i0 = ((p & ~(m - 1)) << 1) | (p & (m - 1));
                int i1 = i0 | m;
                float ar = sr[i0], ai = si[i0], br = sr[i1], bi = si[i1];
                sr[i0] = u00r*ar - u00i*ai + u01r*br - u01i*bi;
                si[i0] = u00r*ai + u00i*ar + u01r*bi + u01i*br;
                sr[i1] = u10r*ar - u10i*ai + u11r*br - u11i*bi;
                si[i1] = u10r*ai + u10i*ar + u11r*bi + u11i*br;
            }
            __syncthreads();
        }
    }

    // QFT_MAT[j,k] = exp(+2*pi*i*j*k/1024)/32 -> radix-2 DIT FFT (+i twiddles)
    for (int i = tid; i < 1024; i += 256) {
        int r = (int)(__brev((unsigned)i) >> 22);
        if (r > i) {
            float tr = sr[i]; sr[i] = sr[r]; sr[r] = tr;
            float ti = si[i]; si[i] = si[r]; si[r] = ti;
        }
    }
    __syncthreads();
    for (int st = 1; st <= 10; ++st) {
        int hf = 1 << (st - 1);
        float astep = 6.28318530717958647f / (float)(1 << st);
        for (int p = tid; p < 512; p += 256) {
            int j2 = p & (hf - 1);
            int i0 = ((p >> (st - 1)) << st) | j2;
            int i1 = i0 + hf;
            float ang = astep * (float)j2;
            float sw, cw;
            __sincosf(ang, &sw, &cw);
            float br2 = sr[i1], bi2 = si[i1];
            float tr = cw*br2 - sw*bi2;
            float ti = cw*bi2 + sw*br2;
            float ur = sr[i0], ui = si[i0];
            sr[i0] = ur + tr; si[i0] = ui + ti;
            sr[i1] = ur - tr; si[i1] = ui - ti;
        }
        __syncthreads();
    }
    for (int k = tid; k < 1024; k += 256) {
        Wh[(size_t)jb * 2048 + 2*k]     = (_Float16)(sr[k] * 0.03125f);
        Wh[(size_t)jb * 2048 + 2*k + 1] = (_Float16)(si[k] * 0.03125f);
    }
}

// ---------------------------------------------------------------------------
// Kernel 1b: Bt[n][j] = Wh[j][n]   ([2048][1024] fp16, K-contiguous rows)
// ---------------------------------------------------------------------------
__global__ __launch_bounds__(256) void transpose_kernel(const _Float16* __restrict__ Wh,
                                                        _Float16* __restrict__ Bt)
{
    __shared__ _Float16 tile[32][33];
    const int bx = blockIdx.x;   // n tile (64)
    const int by = blockIdx.y;   // j tile (32)
    const int tx = threadIdx.x;  // 32
    const int ty = threadIdx.y;  // 8
    #pragma unroll
    for (int i = 0; i < 4; ++i) {
        int r = ty + 8*i;
        tile[r][tx] = Wh[(size_t)(by*32 + r) * 2048 + bx*32 + tx];
    }
    __syncthreads();
    #pragma unroll
    for (int i = 0; i < 4; ++i) {
        int r = ty + 8*i;
        Bt[(size_t)(bx*32 + r) * 1024 + by*32 + tx] = tile[tx][r];
    }
}

// ---------------------------------------------------------------------------
// Kernel 2: GEMM  Sh[8192][2048] = Xh[8192][1024] * Bt^T  (fp16 in, fp32 acc,
// fp16 out).  128x128 tile, BK=64 (16 k-iters), global_load_lds width 16,
// XOR-swizzled LDS (swizzle applied on the global-address side to keep the
// wave-uniform base + 16B*lane layout global_load_lds requires).
// ---------------------------------------------------------------------------
__global__ __launch_bounds__(256, 2) void gemm_kernel(const _Float16* __restrict__ A,
                                                      const _Float16* __restrict__ Bt,
                                                      _Float16* __restrict__ C)
{
    __shared__ __align__(16) _Float16 As[128][64];
    __shared__ __align__(16) _Float16 Bs[128][64];
    const int tid  = threadIdx.x;
    const int wave = tid >> 6;
    const int lane = tid & 63;
    const int m0 = blockIdx.y * 128;
    const int n0 = blockIdx.x * 128;

    // staging: wave w, instr t covers rows 32w+8t .. 32w+8t+7.
    // lane l -> row offset (l>>3), global k-chunk ((l&7) ^ (l>>3))  [swizzle]
    const int srow = lane >> 3;                 // 0..7
    const int schk = (lane & 7) ^ srow;         // swizzled chunk
    const _Float16* gA = A  + (size_t)(m0 + 32*wave + srow) * 1024 + schk * 8;
    const _Float16* gB = Bt + (size_t)(n0 + 32*wave + srow) * 1024 + schk * 8;
    _Float16* lA = &As[0][0] + wave*2048 + lane*8;
    _Float16* lB = &Bs[0][0] + wave*2048 + lane*8;

    // fragment indexing (verified layouts: A row=lane&15, k=(lane>>4)*8+j;
    // C/D col=lane&15, row=(lane>>4)*4+reg)
    const int fr = lane & 15;
    const int fc = lane >> 4;
    const int sx = fr & 7;          // de-swizzle constant for fragment reads
    const int wm = (wave >> 1) * 64;
    const int wn = (wave & 1) * 64;

    floatx4 acc[4][4];
    #pragma unroll
    for (int i = 0; i < 4; ++i)
        #pragma unroll
        for (int j = 0; j < 4; ++j)
            acc[i][j] = (floatx4){0.f, 0.f, 0.f, 0.f};

    for (int kt = 0; kt < 16; ++kt) {
        #pragma unroll
        for (int t = 0; t < 4; ++t) {
            __builtin_amdgcn_global_load_lds(GLB_CAST(gA + (size_t)t*8*1024), LDS_CAST(lA + t*512), 16, 0, 0);
            __builtin_amdgcn_global_load_lds(GLB_CAST(gB + (size_t)t*8*1024), LDS_CAST(lB + t*512), 16, 0, 0);
        }
        gA += 64; gB += 64;
        __syncthreads();
        #pragma unroll
        for (int kh = 0; kh < 2; ++kh) {
            half8_t af[4], bf[4];
            #pragma unroll
            for (int i = 0; i < 4; ++i)
                af[i] = *(const half8_t*)&As[wm + i*16 + fr][((kh*4 + fc) ^ sx) * 8];
            #pragma unroll
            for (int i = 0; i < 4; ++i)
                bf[i] = *(const half8_t*)&Bs[wn + i*16 + fr][((kh*4 + fc) ^ sx) * 8];
            #pragma unroll
            for (int mi = 0; mi < 4; ++mi)
                #pragma unroll
                for (int ni = 0; ni < 4; ++ni)
                    acc[mi][ni] = __builtin_amdgcn_mfma_f32_16x16x32_f16(af[mi], bf[ni], acc[mi][ni], 0, 0, 0);
        }
        __syncthreads();
    }

    #pragma unroll
    for (int mi = 0; mi < 4; ++mi) {
        #pragma unroll
        for (int r = 0; r < 4; ++r) {
            int row = m0 + wm + mi*16 + fc*4 + r;
            _Float16* cp = C + (size_t)row * 2048 + n0 + wn + fr;
            #pragma unroll
            for (int ni = 0; ni < 4; ++ni)
                cp[ni*16] = (_Float16)acc[mi][ni][r];
        }
    }
}

// ---------------------------------------------------------------------------
// Kernel 3: expectations from S.  One WAVE per batch row; lane l owns the 16
// complex amps k = l*16 + i in registers.
//   k-bits 0..3  (qubits 9..6): intra-lane pairs, pure register math.
//   k-bits 4..9  (qubits 5..0): lane-XOR {1,2,4,8,16,32}; partner chunk
//     fetched from a 16B-XOR-swizzled wave-private LDS copy of the row.
//   Reduction: LDS transpose reusing the SAME LDS region.  Zero barriers.
//   __launch_bounds__(128, 4): 128-VGPR budget so c[16]+accumulators stay
//   in registers (R2 post-mortem: default budget=60 VGPR spilled ~63 MB of
//   scratch traffic to HBM -> kernel was spill-bound).
// ---------------------------------------------------------------------------
__global__ __launch_bounds__(128, 4) void expect_kernel(const _Float16* __restrict__ Sh,
                                                        float* __restrict__ out)
{
    __shared__ __align__(16) float buf[2][2176];   // per-wave: row(2048) / pt(2112) alias
    const int tid = threadIdx.x;
    const int w = tid >> 6, l = tid & 63;
    const int row = blockIdx.x * 2 + w;
    float* bw = buf[w];

    // ---- load own 16 complex amps (64B contiguous per lane) -> registers
    const _Float16* src = Sh + (size_t)row * 2048 + l * 32;
    float2 c[16];
    #pragma unroll
    for (int t = 0; t < 4; ++t) {
        half8_t v = ((const half8_t*)src)[t];
        #pragma unroll
        for (int u = 0; u < 4; ++u)
            c[t*4 + u] = make_float2((float)v[2*u], (float)v[2*u + 1]);
    }

    // ---- stage to swizzled LDS: unit j (2 complex) at slot l*8 + (j ^ (l&7))
    #pragma unroll
    for (int j = 0; j < 8; ++j) {
        int su = l*8 + (j ^ (l & 7));
        ((float4*)bw)[su] = make_float4(c[2*j].x, c[2*j].y, c[2*j+1].x, c[2*j+1].y);
    }

    float P2s = 0.f;
    #pragma unroll
    for (int i = 0; i < 16; ++i)
        P2s += c[i].x*c[i].x + c[i].y*c[i].y;

    float cr[10], ci[10], cz[10];
    #pragma unroll
    for (int q = 0; q < 10; ++q) { cr[q] = 0.f; ci[q] = 0.f; cz[q] = 0.f; }

    // intra-lane qubits: k-bit p = 0..3  ->  q = 9-p   (|c|^2 recomputed
    // inline instead of a p2[16] array: -16 live VGPRs)
    #pragma unroll
    for (int p = 0; p < 4; ++p) {
        const int m = 1 << p;
        const int q = 9 - p;
        #pragma unroll
        for (int i = 0; i < 16; ++i) {
            if (i & m) continue;
            const int j = i | m;
            cr[q] += c[i].x*c[j].x + c[i].y*c[j].y;
            ci[q] += c[i].x*c[j].y - c[i].y*c[j].x;
            cz[q] += (c[i].x*c[i].x + c[i].y*c[i].y) - (c[j].x*c[j].x + c[j].y*c[j].y);
        }
    }

    // cross-lane qubits: lane-bit e (k-bit 4+e) -> q = 5-e
    // (wave-internal LDS ordering: no barrier needed)
    #pragma unroll
    for (int e = 0; e < 6; ++e) {
        const int q = 5 - e;
        const int part = l ^ (1 << e);
        const int mybit = (l >> e) & 1;
        const float sgn = mybit ? -1.f : 1.f;
        const int j0 = mybit ? 4 : 0;   // my half of the pair's units
        float rr = 0.f, ii = 0.f;
        #pragma unroll
        for (int j = 0; j < 4; ++j) {
            const int ju = j0 + j;
            const int su = part*8 + (ju ^ (part & 7));
            float4 f = ((const float4*)bw)[su];
            float2 m0 = c[2*ju], m1 = c[2*ju + 1];
            rr += m0.x*f.x + m0.y*f.y;
            ii += m0.x*f.y - m0.y*f.x;
            rr += m1.x*f.z + m1.y*f.w;
            ii += m1.x*f.w - m1.y*f.z;
        }
        cr[q] += rr;
        ci[q] += sgn * ii;
        cz[q] += sgn * P2s;
    }

    // ---- reduction: transpose through the SAME LDS region (row buffer dead)
    #pragma unroll
    for (int q = 0; q < 10; ++q) {
        bw[l*33 + q]      = cr[q];
        bw[l*33 + 10 + q] = ci[q];
        bw[l*33 + 20 + q] = cz[q];
    }

    if (l < 60) {
        const int o = (l < 30) ? l : l - 30;
        const int h = (l < 30) ? 0 : 32;
        float s = 0.f;
        #pragma unroll
        for (int jj = 0; jj < 32; ++jj)
            s += bw[(h + jj)*33 + o];
        float s2 = __shfl(s, (l < 30) ? (l + 30) : (l - 30));
        if (l < 30) {
            float v = s + s2;
            if (o < 20) v *= 2.0f;
            out[(size_t)row * 30 + o] = v;
        }
    }
}

// ---------------------------------------------------------------------------
extern "C" void kernel_launch(void* const* d_in, const int* in_sizes, int n_in,
                              void* d_out, int out_size, void* d_ws, size_t ws_size,
                              hipStream_t stream) {
    const float* x = (const float*)d_in[0];   // [8192][1024]
    const float* w = (const float*)d_in[1];   // [10][4]
    float* out = (float*)d_out;               // [8192][30]
    char* ws = (char*)d_ws;
    // workspace layout (56 MB total):
    _Float16* Wh = (_Float16*)(ws);                         //  4 MB [1024][2048]
    _Float16* Bt = (_Float16*)(ws + ((size_t)4  << 20));    //  4 MB [2048][1024]
    _Float16* Xh = (_Float16*)(ws + ((size_t)8  << 20));    // 16 MB [8192][1024]
    _Float16* Sh = (_Float16*)(ws + ((size_t)24 << 20));    // 32 MB [8192][2048]

    prep_kernel<<<9216, 256, 0, stream>>>(w, x, Wh, Xh);
    transpose_kernel<<<dim3(64, 32), dim3(32, 8), 0, stream>>>(Wh, Bt);
    gemm_kernel<<<dim3(16, 64), 256, 0, stream>>>(Xh, Bt, Sh);
    expect_kernel<<<4096, 128, 0, stream>>>(Sh, out);
}